// Round 1
// baseline (372.206 us; speedup 1.0000x reference)
//
#include <hip/hip_runtime.h>
#include <hip/hip_bf16.h>
#include <cstdint>
#include <cstddef>

// Shapes: b=8, n=8, p=q=64, x=32, y=32, d=8  -> k = x*256+y*8+d in [0,8192)
// Q,K,V: [bn=64][64][8192] fp32.  out: [b][p][xyd][n] fp32 (transposed).
// scores[bn][p][q] = dot_k(Q,K)/1024 -> softmax over q -> out = attn @ V.

#define BKK 32
#define LDS_STRIDE 68   // 68 % 32 == 4 -> conflict-light, float4-aligned

// ---------------- Kernel A: partial QK^T ----------------
// grid (bn=64, kchunks), 256 threads. partial[ch][bn][p][q]
__global__ __launch_bounds__(256) void qk_partial_kernel(
    const float* __restrict__ Q, const float* __restrict__ K,
    float* __restrict__ partial, int clen)
{
    __shared__ float As[BKK][LDS_STRIDE];  // [kk][p]
    __shared__ float Bs[BKK][LDS_STRIDE];  // [kk][q]
    const int bn  = blockIdx.x;
    const int ch  = blockIdx.y;
    const int tid = threadIdx.x;
    const float* Qb = Q + (size_t)bn * 64 * 8192;
    const float* Kb = K + (size_t)bn * 64 * 8192;
    const int k0 = ch * clen;

    const int lp  = tid >> 2;        // 0..63 : row this thread stages
    const int lk0 = (tid & 3) * 4;   // 0,4,8,12 : first float4 col

    const int r0 = (tid >> 4) * 4;   // output sub-tile rows (p)
    const int c0 = (tid & 15) * 4;   // output sub-tile cols (q)

    float acc[4][4];
    #pragma unroll
    for (int i = 0; i < 4; ++i)
        #pragma unroll
        for (int j = 0; j < 4; ++j) acc[i][j] = 0.f;

    for (int kb = 0; kb < clen; kb += BKK) {
        const int kbase = k0 + kb;
        // global loads (coalesced float4)
        const float4 qa = *(const float4*)&Qb[(size_t)lp * 8192 + kbase + lk0];
        const float4 qc = *(const float4*)&Qb[(size_t)lp * 8192 + kbase + lk0 + 16];
        const float4 ka = *(const float4*)&Kb[(size_t)lp * 8192 + kbase + lk0];
        const float4 kc = *(const float4*)&Kb[(size_t)lp * 8192 + kbase + lk0 + 16];
        __syncthreads();  // protect previous iteration's LDS reads
        As[lk0 + 0][lp] = qa.x;  As[lk0 + 1][lp] = qa.y;
        As[lk0 + 2][lp] = qa.z;  As[lk0 + 3][lp] = qa.w;
        As[lk0 + 16][lp] = qc.x; As[lk0 + 17][lp] = qc.y;
        As[lk0 + 18][lp] = qc.z; As[lk0 + 19][lp] = qc.w;
        Bs[lk0 + 0][lp] = ka.x;  Bs[lk0 + 1][lp] = ka.y;
        Bs[lk0 + 2][lp] = ka.z;  Bs[lk0 + 3][lp] = ka.w;
        Bs[lk0 + 16][lp] = kc.x; Bs[lk0 + 17][lp] = kc.y;
        Bs[lk0 + 18][lp] = kc.z; Bs[lk0 + 19][lp] = kc.w;
        __syncthreads();
        #pragma unroll
        for (int kk = 0; kk < BKK; ++kk) {
            const float4 av = *(const float4*)&As[kk][r0];
            const float4 bv = *(const float4*)&Bs[kk][c0];
            const float a4[4] = {av.x, av.y, av.z, av.w};
            const float b4[4] = {bv.x, bv.y, bv.z, bv.w};
            #pragma unroll
            for (int i = 0; i < 4; ++i)
                #pragma unroll
                for (int j = 0; j < 4; ++j)
                    acc[i][j] = fmaf(a4[i], b4[j], acc[i][j]);
        }
    }

    float* pb = partial + (((size_t)ch * 64 + bn) * 64) * 64;
    #pragma unroll
    for (int i = 0; i < 4; ++i) {
        float4 v;
        v.x = acc[i][0]; v.y = acc[i][1]; v.z = acc[i][2]; v.w = acc[i][3];
        *(float4*)&pb[(size_t)(r0 + i) * 64 + c0] = v;
    }
}

// ---------------- Kernel B: reduce partials + softmax ----------------
// grid 1024, 256 threads = 4 waves, one row (bn*64+p) per wave; lane = q.
__global__ __launch_bounds__(256) void softmax_kernel(
    float* __restrict__ ws, const unsigned char* __restrict__ mask, int kchunks)
{
    const int row  = blockIdx.x * 4 + (threadIdx.x >> 6);
    const int q    = threadIdx.x & 63;
    float s = 0.f;
    for (int c = 0; c < kchunks; ++c)
        s += ws[((size_t)c * 4096 + row) * 64 + q];
    s *= (1.0f / 1024.0f);
    const int b = row >> 9;  // row = ((b*8+n)*64+p) -> b = row/512
    if (mask[b * 64 + q]) s = -__builtin_inff();
    float m = s;
    #pragma unroll
    for (int off = 32; off; off >>= 1) m = fmaxf(m, __shfl_xor(m, off));
    const float e = __expf(s - m);
    float sum = e;
    #pragma unroll
    for (int off = 32; off; off >>= 1) sum += __shfl_xor(sum, off);
    ws[(size_t)row * 64 + q] = e / sum;   // attn written over partial[0]
}

// ---------------- Kernel C: PV + transposed store ----------------
// grid (chunks=128, b=8), 512 threads = 8 waves, wave w handles n = w.
// Each lane owns one xyd and all 64 p-accumulators.
__global__ __launch_bounds__(512) void pv_kernel(
    const float* __restrict__ V, const float* __restrict__ attn,
    float* __restrict__ out)
{
    const int b     = blockIdx.y;
    const int chunk = blockIdx.x;
    const int tid   = threadIdx.x;
    const int n     = __builtin_amdgcn_readfirstlane(tid >> 6);  // wave-uniform
    const int lane  = tid & 63;
    const int xyd   = chunk * 64 + lane;

    const float* Vb = V + (size_t)(b * 8 + n) * 64 * 8192;
    const float* Ab = attn + (size_t)(b * 8 + n) * 64 * 64;

    float acc[64];
    #pragma unroll
    for (int p = 0; p < 64; ++p) acc[p] = 0.f;

    for (int qc = 0; qc < 4; ++qc) {
        float v[16];
        #pragma unroll
        for (int j = 0; j < 16; ++j)
            v[j] = Vb[(size_t)(qc * 16 + j) * 8192 + xyd];
        #pragma unroll
        for (int p = 0; p < 64; ++p) {
            const float* ap = Ab + p * 64 + qc * 16;  // wave-uniform -> s_load
            #pragma unroll
            for (int j = 0; j < 16; ++j)
                acc[p] = fmaf(ap[j], v[j], acc[p]);
        }
    }

    // out[b][p][xyd][n]; all 8 n-waves of this block cover the same lines.
    float* ob = out + (size_t)b * 4194304 + (size_t)chunk * 64 * 8 + n;
    #pragma unroll
    for (int p = 0; p < 64; ++p)
        ob[(size_t)p * 65536 + lane * 8] = acc[p];
}

extern "C" void kernel_launch(void* const* d_in, const int* in_sizes, int n_in,
                              void* d_out, int out_size, void* d_ws, size_t ws_size,
                              hipStream_t stream)
{
    const float* Q = (const float*)d_in[0];
    const float* K = (const float*)d_in[1];
    const float* V = (const float*)d_in[2];
    const unsigned char* mask = (const unsigned char*)d_in[3];
    float* out = (float*)d_out;
    float* ws  = (float*)d_ws;

    // partial needs kchunks * 4096 * 64 * 4 bytes = kchunks MB
    int kchunks = 16;
    while (kchunks > 1 &&
           (size_t)kchunks * 4096 * 64 * sizeof(float) > ws_size)
        kchunks >>= 1;
    const int clen = 8192 / kchunks;

    qk_partial_kernel<<<dim3(64, kchunks), 256, 0, stream>>>(Q, K, ws, clen);
    softmax_kernel<<<1024, 256, 0, stream>>>(ws, mask, kchunks);
    pv_kernel<<<dim3(128, 8), 512, 0, stream>>>(V, ws, out);
}

// Round 2
// 302.167 us; speedup vs baseline: 1.2318x; 1.2318x over previous
//
#include <hip/hip_runtime.h>
#include <hip/hip_bf16.h>
#include <cstdint>
#include <cstddef>

// Shapes: b=8, n=8, p=q=64, x=32, y=32, d=8  -> k = x*256+y*8+d in [0,8192)
// Q,K,V: [bn=64][64][8192] fp32.  out: [b][p][xyd][n] fp32 (transposed).
// scores[bn][p][q] = dot_k(Q,K)/1024 -> softmax over q -> out = attn @ V.

#define BKK 32
#define LDS_STRIDE 68   // 68 % 32 == 4 -> conflict-light, float4-aligned

// ---------------- Kernel A: partial QK^T ----------------
// grid (bn=64, kchunks), 256 threads. partial[ch][bn][p][q]
__global__ __launch_bounds__(256) void qk_partial_kernel(
    const float* __restrict__ Q, const float* __restrict__ K,
    float* __restrict__ partial, int clen)
{
    __shared__ float As[BKK][LDS_STRIDE];  // [kk][p]
    __shared__ float Bs[BKK][LDS_STRIDE];  // [kk][q]
    const int bn  = blockIdx.x;
    const int ch  = blockIdx.y;
    const int tid = threadIdx.x;
    const float* Qb = Q + (size_t)bn * 64 * 8192;
    const float* Kb = K + (size_t)bn * 64 * 8192;
    const int k0 = ch * clen;

    const int lp  = tid >> 2;        // 0..63 : row this thread stages
    const int lk0 = (tid & 3) * 4;   // 0,4,8,12 : first float4 col

    const int r0 = (tid >> 4) * 4;   // output sub-tile rows (p)
    const int c0 = (tid & 15) * 4;   // output sub-tile cols (q)

    float acc[4][4];
    #pragma unroll
    for (int i = 0; i < 4; ++i)
        #pragma unroll
        for (int j = 0; j < 4; ++j) acc[i][j] = 0.f;

    for (int kb = 0; kb < clen; kb += BKK) {
        const int kbase = k0 + kb;
        // global loads (coalesced float4)
        const float4 qa = *(const float4*)&Qb[(size_t)lp * 8192 + kbase + lk0];
        const float4 qc = *(const float4*)&Qb[(size_t)lp * 8192 + kbase + lk0 + 16];
        const float4 ka = *(const float4*)&Kb[(size_t)lp * 8192 + kbase + lk0];
        const float4 kc = *(const float4*)&Kb[(size_t)lp * 8192 + kbase + lk0 + 16];
        __syncthreads();  // protect previous iteration's LDS reads
        As[lk0 + 0][lp] = qa.x;  As[lk0 + 1][lp] = qa.y;
        As[lk0 + 2][lp] = qa.z;  As[lk0 + 3][lp] = qa.w;
        As[lk0 + 16][lp] = qc.x; As[lk0 + 17][lp] = qc.y;
        As[lk0 + 18][lp] = qc.z; As[lk0 + 19][lp] = qc.w;
        Bs[lk0 + 0][lp] = ka.x;  Bs[lk0 + 1][lp] = ka.y;
        Bs[lk0 + 2][lp] = ka.z;  Bs[lk0 + 3][lp] = ka.w;
        Bs[lk0 + 16][lp] = kc.x; Bs[lk0 + 17][lp] = kc.y;
        Bs[lk0 + 18][lp] = kc.z; Bs[lk0 + 19][lp] = kc.w;
        __syncthreads();
        #pragma unroll
        for (int kk = 0; kk < BKK; ++kk) {
            const float4 av = *(const float4*)&As[kk][r0];
            const float4 bv = *(const float4*)&Bs[kk][c0];
            const float a4[4] = {av.x, av.y, av.z, av.w};
            const float b4[4] = {bv.x, bv.y, bv.z, bv.w};
            #pragma unroll
            for (int i = 0; i < 4; ++i)
                #pragma unroll
                for (int j = 0; j < 4; ++j)
                    acc[i][j] = fmaf(a4[i], b4[j], acc[i][j]);
        }
    }

    float* pb = partial + (((size_t)ch * 64 + bn) * 64) * 64;
    #pragma unroll
    for (int i = 0; i < 4; ++i) {
        float4 v;
        v.x = acc[i][0]; v.y = acc[i][1]; v.z = acc[i][2]; v.w = acc[i][3];
        *(float4*)&pb[(size_t)(r0 + i) * 64 + c0] = v;
    }
}

// ---------------- Kernel B: reduce partials + softmax ----------------
// grid 1024, 256 threads = 4 waves, one row (bn*64+p) per wave; lane = q.
__global__ __launch_bounds__(256) void softmax_kernel(
    float* __restrict__ ws, const unsigned char* __restrict__ mask, int kchunks)
{
    const int row  = blockIdx.x * 4 + (threadIdx.x >> 6);
    const int q    = threadIdx.x & 63;
    float s = 0.f;
    for (int c = 0; c < kchunks; ++c)
        s += ws[((size_t)c * 4096 + row) * 64 + q];
    s *= (1.0f / 1024.0f);
    const int b = row >> 9;  // row = ((b*8+n)*64+p) -> b = row/512
    if (mask[b * 64 + q]) s = -__builtin_inff();
    float m = s;
    #pragma unroll
    for (int off = 32; off; off >>= 1) m = fmaxf(m, __shfl_xor(m, off));
    const float e = __expf(s - m);
    float sum = e;
    #pragma unroll
    for (int off = 32; off; off >>= 1) sum += __shfl_xor(sum, off);
    ws[(size_t)row * 64 + q] = e / sum;   // attn written over partial[0]
}

// ---------------- Kernel C: PV + transposed store ----------------
// grid (chunks=128, b=8), 512 threads = 8 waves, wave w handles n = w.
// Each lane owns one xyd and all 64 p-accumulators (REGISTERS — forced).
// Output staged through LDS so global stores are fully coalesced float4.
__global__ __launch_bounds__(512, 2) void pv_kernel(
    const float* __restrict__ V, const float* __restrict__ attn,
    float* __restrict__ out)
{
    // [pp][xx*9 + n] : pad 8->9 floats per xx so LDS access is 2-way (free)
    __shared__ float ob[8][64 * 9];

    const int b     = blockIdx.y;
    const int chunk = blockIdx.x;
    const int tid   = threadIdx.x;
    const int w     = tid >> 6;
    const int n     = __builtin_amdgcn_readfirstlane(w);  // wave-uniform
    const int lane  = tid & 63;
    const int xyd   = chunk * 64 + lane;

    const float* Vb = V + (size_t)(b * 8 + n) * 64 * 8192;
    const float* Ab = attn + (size_t)(b * 8 + n) * 64 * 64;

    float acc[64];
    #pragma unroll 64
    for (int p = 0; p < 64; ++p) acc[p] = 0.f;

    for (int qc = 0; qc < 4; ++qc) {
        float v[16];
        #pragma unroll 16
        for (int j = 0; j < 16; ++j)
            v[j] = Vb[(size_t)(qc * 16 + j) * 8192 + xyd];
        #pragma unroll 64
        for (int p = 0; p < 64; ++p) {
            const float* ap = Ab + p * 64 + qc * 16;  // wave-uniform -> s_load
            #pragma unroll 16
            for (int j = 0; j < 16; ++j)
                acc[p] = fmaf(ap[j], v[j], acc[p]);
        }
    }

    // ---- Coalesced store via LDS transpose, 8 p-rows at a time ----
    // out[b][p][xyd][n]: floats for (b, p, chunk) = 512 contiguous floats.
    #pragma unroll
    for (int pg = 0; pg < 8; ++pg) {
        __syncthreads();  // protect previous pg's reads
        #pragma unroll
        for (int pp = 0; pp < 8; ++pp)
            ob[pp][lane * 9 + w] = acc[pg * 8 + pp];   // static acc index
        __syncthreads();
        // wave w stores row p = pg*8 + w : lane covers (xx=lane, n=0..7)
        float t0 = ob[w][lane * 9 + 0];
        float t1 = ob[w][lane * 9 + 1];
        float t2 = ob[w][lane * 9 + 2];
        float t3 = ob[w][lane * 9 + 3];
        float t4 = ob[w][lane * 9 + 4];
        float t5 = ob[w][lane * 9 + 5];
        float t6 = ob[w][lane * 9 + 6];
        float t7 = ob[w][lane * 9 + 7];
        float* op = out + (size_t)b * 4194304 + (size_t)(pg * 8 + w) * 65536
                        + chunk * 512 + lane * 8;
        float4 lo; lo.x = t0; lo.y = t1; lo.z = t2; lo.w = t3;
        float4 hi; hi.x = t4; hi.y = t5; hi.z = t6; hi.w = t7;
        *(float4*)op       = lo;
        *((float4*)op + 1) = hi;
    }
}

extern "C" void kernel_launch(void* const* d_in, const int* in_sizes, int n_in,
                              void* d_out, int out_size, void* d_ws, size_t ws_size,
                              hipStream_t stream)
{
    const float* Q = (const float*)d_in[0];
    const float* K = (const float*)d_in[1];
    const float* V = (const float*)d_in[2];
    const unsigned char* mask = (const unsigned char*)d_in[3];
    float* out = (float*)d_out;
    float* ws  = (float*)d_ws;

    // partial needs kchunks * 4096 * 64 * 4 bytes = kchunks MB
    int kchunks = 16;
    while (kchunks > 1 &&
           (size_t)kchunks * 4096 * 64 * sizeof(float) > ws_size)
        kchunks >>= 1;
    const int clen = 8192 / kchunks;

    qk_partial_kernel<<<dim3(64, kchunks), 256, 0, stream>>>(Q, K, ws, clen);
    softmax_kernel<<<1024, 256, 0, stream>>>(ws, mask, kchunks);
    pv_kernel<<<dim3(128, 8), 512, 0, stream>>>(V, ws, out);
}

// Round 3
// 149.950 us; speedup vs baseline: 2.4822x; 2.0151x over previous
//
#include <hip/hip_runtime.h>
#include <hip/hip_bf16.h>
#include <cstdint>
#include <cstddef>

// Shapes: b=8, n=8, p=q=64, x=32, y=32, d=8  -> xyd = x*256+y*8+d in [0,8192)
// Q,K,V: [bn=64][64][8192] fp32.  out: [b][p][xyd][n] fp32 (transposed).
// scores[bn][p][q] = dot_k(Q,K)/1024 -> softmax over q -> out = attn @ V.

typedef __attribute__((ext_vector_type(4))) float f32x4;
typedef __attribute__((ext_vector_type(8))) short bf16x8;
typedef __attribute__((ext_vector_type(4))) short shortx4;

__device__ __forceinline__ unsigned short f2bf(float x) {
    unsigned int u = __builtin_bit_cast(unsigned int, x);
    u += 0x7FFFu + ((u >> 16) & 1u);     // RTNE
    return (unsigned short)(u >> 16);
}

#define BKK 32
#define LDS_STRIDE 68   // 68 % 32 == 4 -> conflict-light, float4-aligned

// ---------------- Kernel A: partial QK^T (unchanged, proven) ----------------
__global__ __launch_bounds__(256) void qk_partial_kernel(
    const float* __restrict__ Q, const float* __restrict__ K,
    float* __restrict__ partial, int clen)
{
    __shared__ float As[BKK][LDS_STRIDE];
    __shared__ float Bs[BKK][LDS_STRIDE];
    const int bn  = blockIdx.x;
    const int ch  = blockIdx.y;
    const int tid = threadIdx.x;
    const float* Qb = Q + (size_t)bn * 64 * 8192;
    const float* Kb = K + (size_t)bn * 64 * 8192;
    const int k0 = ch * clen;

    const int lp  = tid >> 2;
    const int lk0 = (tid & 3) * 4;
    const int r0 = (tid >> 4) * 4;
    const int c0 = (tid & 15) * 4;

    float acc[4][4];
    #pragma unroll
    for (int i = 0; i < 4; ++i)
        #pragma unroll
        for (int j = 0; j < 4; ++j) acc[i][j] = 0.f;

    for (int kb = 0; kb < clen; kb += BKK) {
        const int kbase = k0 + kb;
        const float4 qa = *(const float4*)&Qb[(size_t)lp * 8192 + kbase + lk0];
        const float4 qc = *(const float4*)&Qb[(size_t)lp * 8192 + kbase + lk0 + 16];
        const float4 ka = *(const float4*)&Kb[(size_t)lp * 8192 + kbase + lk0];
        const float4 kc = *(const float4*)&Kb[(size_t)lp * 8192 + kbase + lk0 + 16];
        __syncthreads();
        As[lk0 + 0][lp] = qa.x;  As[lk0 + 1][lp] = qa.y;
        As[lk0 + 2][lp] = qa.z;  As[lk0 + 3][lp] = qa.w;
        As[lk0 + 16][lp] = qc.x; As[lk0 + 17][lp] = qc.y;
        As[lk0 + 18][lp] = qc.z; As[lk0 + 19][lp] = qc.w;
        Bs[lk0 + 0][lp] = ka.x;  Bs[lk0 + 1][lp] = ka.y;
        Bs[lk0 + 2][lp] = ka.z;  Bs[lk0 + 3][lp] = ka.w;
        Bs[lk0 + 16][lp] = kc.x; Bs[lk0 + 17][lp] = kc.y;
        Bs[lk0 + 18][lp] = kc.z; Bs[lk0 + 19][lp] = kc.w;
        __syncthreads();
        #pragma unroll
        for (int kk = 0; kk < BKK; ++kk) {
            const float4 av = *(const float4*)&As[kk][r0];
            const float4 bv = *(const float4*)&Bs[kk][c0];
            const float a4[4] = {av.x, av.y, av.z, av.w};
            const float b4[4] = {bv.x, bv.y, bv.z, bv.w};
            #pragma unroll
            for (int i = 0; i < 4; ++i)
                #pragma unroll
                for (int j = 0; j < 4; ++j)
                    acc[i][j] = fmaf(a4[i], b4[j], acc[i][j]);
        }
    }

    float* pb = partial + (((size_t)ch * 64 + bn) * 64) * 64;
    #pragma unroll
    for (int i = 0; i < 4; ++i) {
        float4 v;
        v.x = acc[i][0]; v.y = acc[i][1]; v.z = acc[i][2]; v.w = acc[i][3];
        *(float4*)&pb[(size_t)(r0 + i) * 64 + c0] = v;
    }
}

// ---------------- Kernel B: reduce partials + softmax (unchanged) ----------------
__global__ __launch_bounds__(256) void softmax_kernel(
    float* __restrict__ ws, const unsigned char* __restrict__ mask, int kchunks)
{
    const int row  = blockIdx.x * 4 + (threadIdx.x >> 6);
    const int q    = threadIdx.x & 63;
    float s = 0.f;
    for (int c = 0; c < kchunks; ++c)
        s += ws[((size_t)c * 4096 + row) * 64 + q];
    s *= (1.0f / 1024.0f);
    const int b = row >> 9;
    if (mask[b * 64 + q]) s = -__builtin_inff();
    float m = s;
    #pragma unroll
    for (int off = 32; off; off >>= 1) m = fmaxf(m, __shfl_xor(m, off));
    const float e = __expf(s - m);
    float sum = e;
    #pragma unroll
    for (int off = 32; off; off >>= 1) sum += __shfl_xor(sum, off);
    ws[(size_t)row * 64 + q] = e / sum;
}

// ---------------- Kernel C: PV via bf16 MFMA ----------------
// grid (chunk=128, b=8), 512 threads = 8 waves, wave w = n.
// Per wave: D[64p][64xc] = attn[64p][64q] * V[64q][64xc], fp32 acc in 16 f32x4.
// V staged transposed ([xc][q] bf16) in LDS with XOR swizzle; attn A-frags
// loaded directly from global (L2-resident, 1 MB total).
__global__ __launch_bounds__(512, 2) void pv_mfma_kernel(
    const float* __restrict__ V, const float* __restrict__ attn,
    float* __restrict__ out)
{
    __shared__ unsigned char smem[65536];   // phase 1: vt[8][64][64] bf16; phase 2: ob fp32

    const int b     = blockIdx.y;
    const int chunk = blockIdx.x;
    const int tid   = threadIdx.x;
    const int w     = tid >> 6;           // wave = n
    const int lane  = tid & 63;

    const float* Vb = V    + (size_t)(b * 8 + w) * 64 * 8192 + (size_t)chunk * 64;
    const float* Ab = attn + (size_t)(b * 8 + w) * 4096;

    unsigned short* vtn = (unsigned short*)smem + w * 4096;   // this wave's V^T tile

    // ---- stage V chunk -> LDS transposed bf16, swizzled ----
    // lane -> (c = xc-group of 4, qg = q-subgroup of 4 rows)
    const int c  = lane >> 2;
    const int qg = lane & 3;
    #pragma unroll
    for (int s = 0; s < 4; ++s) {
        const int q0 = s * 16 + qg * 4;
        const float4 r0 = *(const float4*)&Vb[(size_t)(q0 + 0) * 8192 + c * 4];
        const float4 r1 = *(const float4*)&Vb[(size_t)(q0 + 1) * 8192 + c * 4];
        const float4 r2 = *(const float4*)&Vb[(size_t)(q0 + 2) * 8192 + c * 4];
        const float4 r3 = *(const float4*)&Vb[(size_t)(q0 + 3) * 8192 + c * 4];
        const float v0[4] = {r0.x, r0.y, r0.z, r0.w};
        const float v1[4] = {r1.x, r1.y, r1.z, r1.w};
        const float v2[4] = {r2.x, r2.y, r2.z, r2.w};
        const float v3[4] = {r3.x, r3.y, r3.z, r3.w};
        #pragma unroll
        for (int cc = 0; cc < 4; ++cc) {
            const int row = c * 4 + cc;       // xc within chunk
            shortx4 pk;
            pk.x = (short)f2bf(v0[cc]);
            pk.y = (short)f2bf(v1[cc]);
            pk.z = (short)f2bf(v2[cc]);
            pk.w = (short)f2bf(v3[cc]);
            // short-unit offset: row*64 + (q ^ ((row&7)<<3) ^ (((row>>3)&3)<<4))
            const int soff = row * 64 + (q0 ^ ((row & 7) << 3) ^ (((row >> 3) & 3) << 4));
            *(shortx4*)(vtn + soff) = pk;
        }
    }

    // ---- A fragments: attn rows, bf16 ----
    const int arow = lane & 15;
    const int q0a  = (lane >> 4) * 8;
    bf16x8 afrag[4][2];
    #pragma unroll
    for (int mt = 0; mt < 4; ++mt) {
        #pragma unroll
        for (int ks = 0; ks < 2; ++ks) {
            const float* ap = Ab + (mt * 16 + arow) * 64 + ks * 32 + q0a;
            const float4 lo = *(const float4*)ap;
            const float4 hi = *(const float4*)(ap + 4);
            bf16x8 f;
            f[0] = (short)f2bf(lo.x); f[1] = (short)f2bf(lo.y);
            f[2] = (short)f2bf(lo.z); f[3] = (short)f2bf(lo.w);
            f[4] = (short)f2bf(hi.x); f[5] = (short)f2bf(hi.y);
            f[6] = (short)f2bf(hi.z); f[7] = (short)f2bf(hi.w);
            afrag[mt][ks] = f;
        }
    }

    // ---- MFMA compute: 16 accumulator fragments (registers, static) ----
    f32x4 acc[4][4];
    #pragma unroll
    for (int mt = 0; mt < 4; ++mt)
        #pragma unroll
        for (int nt = 0; nt < 4; ++nt)
            acc[mt][nt] = (f32x4)(0.f);

    const int bcol = lane & 15;
    const int q0b  = (lane >> 4) * 8;
    #pragma unroll
    for (int nt = 0; nt < 4; ++nt) {
        bf16x8 bfr[2];
        #pragma unroll
        for (int ks = 0; ks < 2; ++ks) {
            const int row  = nt * 16 + bcol;
            const int q0   = ks * 32 + q0b;
            const int soff = row * 64 + (q0 ^ ((row & 7) << 3) ^ (((row >> 3) & 3) << 4));
            bfr[ks] = *(const bf16x8*)(vtn + soff);
        }
        #pragma unroll
        for (int ks = 0; ks < 2; ++ks)
            #pragma unroll
            for (int mt = 0; mt < 4; ++mt)
                acc[mt][nt] = __builtin_amdgcn_mfma_f32_16x16x32_bf16(
                    afrag[mt][ks], bfr[ks], acc[mt][nt], 0, 0, 0);
    }

    // ---- store: D frags -> LDS transpose -> coalesced float4 stores ----
    // D layout per frag: col = lane&15 (xc), row = (lane>>4)*4 + r (p).
    float* ob = (float*)smem;          // [16 p][64 xc][9 (8n + pad)]
    const int pq = lane >> 4;
    const int pl = tid >> 5;           // 0..15 : p-row for store phase
    const int g  = tid & 31;
    #pragma unroll
    for (int mt = 0; mt < 4; ++mt) {
        __syncthreads();               // vt reads (mt=0) / prior ob reads done
        #pragma unroll
        for (int nt = 0; nt < 4; ++nt)
            #pragma unroll
            for (int r = 0; r < 4; ++r) {
                const int prow = pq * 4 + r;
                const int xc   = nt * 16 + (lane & 15);
                ob[prow * 576 + xc * 9 + w] = acc[mt][nt][r];
            }
        __syncthreads();
        // (b, p=mt*16+pl, chunk) -> 512 contiguous floats in out
        float* orow = out + (size_t)b * 4194304 + (size_t)(mt * 16 + pl) * 65536
                          + (size_t)chunk * 512;
        #pragma unroll
        for (int u = 0; u < 4; ++u) {
            const int f0 = g * 4 + u * 128;
            float4 vv;
            vv.x = ob[pl * 576 + ((f0 + 0) >> 3) * 9 + ((f0 + 0) & 7)];
            vv.y = ob[pl * 576 + ((f0 + 1) >> 3) * 9 + ((f0 + 1) & 7)];
            vv.z = ob[pl * 576 + ((f0 + 2) >> 3) * 9 + ((f0 + 2) & 7)];
            vv.w = ob[pl * 576 + ((f0 + 3) >> 3) * 9 + ((f0 + 3) & 7)];
            *(float4*)&orow[f0] = vv;
        }
    }
}

extern "C" void kernel_launch(void* const* d_in, const int* in_sizes, int n_in,
                              void* d_out, int out_size, void* d_ws, size_t ws_size,
                              hipStream_t stream)
{
    const float* Q = (const float*)d_in[0];
    const float* K = (const float*)d_in[1];
    const float* V = (const float*)d_in[2];
    const unsigned char* mask = (const unsigned char*)d_in[3];
    float* out = (float*)d_out;
    float* ws  = (float*)d_ws;

    int kchunks = 16;
    while (kchunks > 1 &&
           (size_t)kchunks * 4096 * 64 * sizeof(float) > ws_size)
        kchunks >>= 1;
    const int clen = 8192 / kchunks;

    qk_partial_kernel<<<dim3(64, kchunks), 256, 0, stream>>>(Q, K, ws, clen);
    softmax_kernel<<<1024, 256, 0, stream>>>(ws, mask, kchunks);
    pv_mfma_kernel<<<dim3(128, 8), 512, 0, stream>>>(V, ws, out);
}